// Round 14
// baseline (83.769 us; speedup 1.0000x reference)
//
#include <hip/hip_runtime.h>

#define HALO 5
#define TW 54              // output cols per tile
#define IW 64              // input cols per tile (= lanes)
#define ROWS 32            // output rows per tile
#define IR (ROWS + 2*HALO) // 42 input rows per tile
#define BATCH 16
#define CH 3
#define H 512
#define W 512
#define HW (H*W)
#define NCT 10             // ceil(512/54) col tiles
#define NST (H/ROWS)       // 16 row strips
#define NBLOCKS (BATCH*NST*NCT)   // 2560
#define CH_TASKS 816       // 6 planes * 8 rows * 17 float4 per chunk
#define CH_F (CH_TASKS*4)  // 3264 floats per chunk buffer

__device__ __forceinline__ void f4add(float4& a, const float4 b) {
    a.x += b.x; a.y += b.y; a.z += b.z; a.w += b.w;
}

__global__ __launch_bounds__(64) void ssim_wave_kernel(
    const float* __restrict__ pred, const float* __restrict__ gt,
    float* __restrict__ partial)
{
    // stage4: double-buffered raw 8-row x 6-plane x 68-col chunks (26.1 KB)
    // vsbuf : 8-deep rotating vertical box sums, rotation-swizzled (8 KB)
    __shared__ float4 stage4[2][CH_TASKS];
    __shared__ float4 vsbuf[8][IW];

    const int lane = threadIdx.x;
    const int bid  = (blockIdx.x & 7) * (NBLOCKS / 8) + (blockIdx.x >> 3);
    const int tc   = bid % NCT;
    const int rest = bid / NCT;
    const int ts   = rest & (NST - 1);
    const int b    = rest / NST;

    const int sstart = tc * TW - HALO;        // first input col of tile
    const int g_dn   = sstart & ~3;           // 16B-aligned staging start
    const int shift  = sstart & 3;
    const int gx     = sstart + lane;         // owned input column
    const int gy0    = ts * ROWS - HALO;      // input row at ri=0
    const bool colok = (unsigned)gx < W;

    const float* __restrict__ pb = pred + (size_t)b * (CH * HW);
    const float* __restrict__ gb = gt   + (size_t)b * (CH * HW);

    // ---- per-lane staging task decode (13 iters x 64 lanes >= 816 tasks) ----
    // task t -> plane p = (t/17)>>3, row = (t/17)&7, quarter q = t%17
    const float* srcNoY[13];
    unsigned rp0 = 0, rp1 = 0;                // packed 3-bit rows
    #pragma unroll
    for (int i = 0; i < 13; ++i) {
        int task = i * 64 + lane;
        if (task > CH_TASKS - 1) task = CH_TASKS - 1;   // dup, write-masked
        const int pr  = task / 17;
        const int q   = task - pr * 17;
        const int p   = pr >> 3;
        const int row = pr & 7;
        const int gx4 = min(max(g_dn + 4 * q, 0), W - 4);
        const float* base = (p < 3) ? (pb + p * HW) : (gb + (p - 3) * HW);
        srcNoY[i] = base + gx4;
        if (i < 10) rp0 |= (unsigned)row << (3 * i);
        else        rp1 |= (unsigned)row << (3 * (i - 10));
    }

    const float inv_n = 1.f/363.f, inv_nm1 = 1.f/362.f;
    const float C1 = 1e-4f, C2 = 9e-4f;

    float4 R[13];                    // staging registers (one chunk in flight)
    float4 ring[11];
    #pragma unroll
    for (int u = 0; u < 11; ++u) ring[u] = make_float4(0.f,0.f,0.f,0.f);
    float4 vs = make_float4(0.f,0.f,0.f,0.f);
    float accl = 0.f;

    const float* sb = (const float*)&stage4[0][0] + shift + lane; // consume base

#define STAGE_LOAD(c) do { \
    const int gyc0_ = gy0 + 8 * (c); \
    _Pragma("unroll") \
    for (int i = 0; i < 13; ++i) { \
        const int row_ = (i < 10) ? (int)((rp0 >> (3*i)) & 7) \
                                  : (int)((rp1 >> (3*(i-10))) & 7); \
        const int gyc_ = min(max(gyc0_ + row_, 0), H - 1); \
        R[i] = *(const float4*)(srcNoY[i] + (gyc_ << 9)); \
    } \
    __builtin_amdgcn_sched_barrier(0); \
} while(0)

#define STAGE_WRITE(c) do { \
    float4* dst_ = &stage4[(c) & 1][lane]; \
    _Pragma("unroll") \
    for (int i = 0; i < 12; ++i) dst_[i * 64] = R[i]; \
    if (lane < CH_TASKS - 768) dst_[12 * 64] = R[12]; \
} while(0)

// consume: 6 ds_read_b32 with literal offsets off shared vaddr sb
#define LV(sB, p, rr) sb[(sB) * CH_F + ((p) * 8 + (rr)) * 68]

#define RS(ri) do { \
    const int rr_ = (ri) & 7; \
    const bool rowok_ = colok && ((unsigned)(gy0 + (ri)) < (unsigned)H); \
    const float m_ = rowok_ ? 1.f : 0.f; \
    const float p0 = LV(((ri)>>3)&1,0,rr_) * m_; \
    const float p1 = LV(((ri)>>3)&1,1,rr_) * m_; \
    const float p2 = LV(((ri)>>3)&1,2,rr_) * m_; \
    const float g0 = LV(((ri)>>3)&1,3,rr_) * m_; \
    const float g1 = LV(((ri)>>3)&1,4,rr_) * m_; \
    const float g2 = LV(((ri)>>3)&1,5,rr_) * m_; \
    float4 q; \
    q.x = p0 + p1 + p2; \
    q.y = g0 + g1 + g2; \
    q.z = fmaf(p0,p0, fmaf(p1,p1, fmaf(p2,p2, fmaf(g0,g0, fmaf(g1,g1, g2*g2))))); \
    q.w = fmaf(p0,g0, fmaf(p1,g1, p2*g2)); \
    vs.x += q.x - ring[(ri)%11].x; \
    vs.y += q.y - ring[(ri)%11].y; \
    vs.z += q.z - ring[(ri)%11].z; \
    vs.w += q.w - ring[(ri)%11].w; \
    ring[(ri)%11] = q; \
    if ((ri) >= 10) vsbuf[((ri)-10)&7][(lane + (((ri)-10)&7)) & 63] = vs; \
} while(0)

#define SSIM_ACC(S, oxv) do { \
    if ((unsigned)(oxv) < W) { \
        const float mu_p = (S).x * inv_n, mu_g = (S).y * inv_n; \
        const float varsum = ((S).z - (S).x*mu_p - (S).y*mu_g) * inv_nm1; \
        const float cov    = ((S).w - (S).x*mu_g) * inv_n; \
        const float num = (2.f*mu_p*mu_g + C1) * (2.f*cov + C2); \
        const float den = (mu_p*mu_p + mu_g*mu_g + C1) * (varsum + C2); \
        accl = fmaf(num, __builtin_amdgcn_rcpf(den + 1e-8f), accl); \
    } \
} while(0)

#define WAVE_LDS_FENCE() asm volatile("s_waitcnt lgkmcnt(0)" ::: "memory")

    auto phase2 = [&]() {
        const int r  = lane & 7;
        const int g  = lane >> 3;
        const int jb = 7 * g;
        const int ox0 = tc * TW + jb;
        float4 B = vsbuf[r][(jb + r) & 63];
        #pragma unroll
        for (int k = 1; k < 11; ++k) f4add(B, vsbuf[r][(jb + k + r) & 63]);
        SSIM_ACC(B, ox0);
        #pragma unroll
        for (int sp = 1; sp < 7; ++sp) {
            if (jb + 10 + sp <= 63) {
                const float4 nw = vsbuf[r][(jb + 10 + sp + r) & 63];
                const float4 od = vsbuf[r][(jb + sp - 1 + r) & 63];
                B.x += nw.x - od.x; B.y += nw.y - od.y;
                B.z += nw.z - od.z; B.w += nw.w - od.w;
                SSIM_ACC(B, ox0 + sp);
            }
        }
    };

    // ---- pipeline: chunk c = input rows 8c..8c+7 (c = 0..5) ----
    STAGE_LOAD(0); STAGE_WRITE(0);        // one full-latency stall (prologue)
    STAGE_LOAD(1);                        // flies over consume of chunk 0

    // c=0
    RS(0); RS(1); RS(2); RS(3); RS(4); RS(5); RS(6); RS(7);
    STAGE_WRITE(1); STAGE_LOAD(2);
    // c=1
    RS(8); RS(9); RS(10); RS(11); RS(12); RS(13); RS(14); RS(15);
    STAGE_WRITE(2); STAGE_LOAD(3);
    // c=2
    RS(16); RS(17); WAVE_LDS_FENCE(); phase2();
    RS(18); RS(19); RS(20); RS(21); RS(22); RS(23);
    STAGE_WRITE(3); STAGE_LOAD(4);
    // c=3
    RS(24); RS(25); WAVE_LDS_FENCE(); phase2();
    RS(26); RS(27); RS(28); RS(29); RS(30); RS(31);
    STAGE_WRITE(4); STAGE_LOAD(5);
    // c=4
    RS(32); RS(33); WAVE_LDS_FENCE(); phase2();
    RS(34); RS(35); RS(36); RS(37); RS(38); RS(39);
    STAGE_WRITE(5);
    // c=5 (rows 42..47 dead)
    RS(40); RS(41); WAVE_LDS_FENCE(); phase2();

    // ---- wave reduce ----
    #pragma unroll
    for (int off = 32; off > 0; off >>= 1) accl += __shfl_down(accl, off);
    if (lane == 0) partial[bid] = accl;

#undef STAGE_LOAD
#undef STAGE_WRITE
#undef LV
#undef RS
#undef SSIM_ACC
#undef WAVE_LDS_FENCE
}

__global__ __launch_bounds__(256) void ssim_final_reduce(
    const float* __restrict__ partial, float* __restrict__ out)
{
    __shared__ float red[4];
    const int tid = threadIdx.x;
    float s = 0.f;
    for (int i = tid; i < NBLOCKS; i += 256) s += partial[i];
    #pragma unroll
    for (int off = 32; off > 0; off >>= 1) s += __shfl_down(s, off);
    if ((tid & 63) == 0) red[tid >> 6] = s;
    __syncthreads();
    if (tid == 0) {
        const float total = red[0] + red[1] + red[2] + red[3];
        out[0] = 1.0f - total * (1.0f / (float)(BATCH * H * W));
    }
}

extern "C" void kernel_launch(void* const* d_in, const int* in_sizes, int n_in,
                              void* d_out, int out_size, void* d_ws, size_t ws_size,
                              hipStream_t stream) {
    const float* pred = (const float*)d_in[0];
    const float* gt   = (const float*)d_in[1];
    float* out        = (float*)d_out;
    float* partial    = (float*)d_ws;

    ssim_wave_kernel<<<NBLOCKS, 64, 0, stream>>>(pred, gt, partial);
    ssim_final_reduce<<<1, 256, 0, stream>>>(partial, out);
}

// Round 15
// 37.921 us; speedup vs baseline: 2.2091x; 2.2091x over previous
//
#include <hip/hip_runtime.h>

#define HALO 5
#define TW 54              // output cols per tile
#define IW 64              // input cols per tile (= lanes)
#define ROWS 32            // output rows per tile
#define IR (ROWS + 2*HALO) // 42 input rows per tile
#define BATCH 16
#define CH 3
#define H 512
#define W 512
#define HW (H*W)
#define NCT 10             // ceil(512/54) col tiles
#define NST (H/ROWS)       // 16 row strips
#define NBLOCKS (BATCH*NST*NCT)   // 2560
#define D 10               // prefetch distance in rows
#define RNG 12             // staging ring rows (>= D+2)

__device__ __forceinline__ void f4add(float4& a, const float4 b) {
    a.x += b.x; a.y += b.y; a.z += b.z; a.w += b.w;
}

__global__ __launch_bounds__(64) void ssim_wave_kernel(
    const float* __restrict__ pred, const float* __restrict__ gt,
    float* __restrict__ partial)
{
    // stage: 12-row x 6-plane x 64-col ring, filled by global_load_lds
    //        (HW layout: wave-uniform base + lane*4 == [slot][plane][lane])
    // vsbuf: 8-deep rotating vertical box sums, rotation-swizzled
    __shared__ float  stage[RNG][6][IW];   // 18 KB
    __shared__ float4 vsbuf[8][IW];        //  8 KB

    const int lane = threadIdx.x;
    const int bid  = (blockIdx.x & 7) * (NBLOCKS / 8) + (blockIdx.x >> 3);
    const int tc   = bid % NCT;
    const int rest = bid / NCT;
    const int ts   = rest & (NST - 1);
    const int b    = rest / NST;

    const int gx   = tc * TW - HALO + lane;   // owned input column
    const int gy0  = ts * ROWS - HALO;        // input row at ri=0
    const bool colok = (unsigned)gx < W;
    const int gxc  = min(max(gx, 0), W - 1);  // clamped column (always valid)

    const float* __restrict__ pb = pred + (size_t)b * (CH * HW);
    const float* __restrict__ gb = gt   + (size_t)b * (CH * HW);
    const float* __restrict__ pb0 = pb;
    const float* __restrict__ pb1 = pb + HW;
    const float* __restrict__ pb2 = pb + 2 * HW;
    const float* __restrict__ gb0 = gb;
    const float* __restrict__ gb1 = gb + HW;
    const float* __restrict__ gb2 = gb + 2 * HW;

    const float inv_n = 1.f/363.f, inv_nm1 = 1.f/362.f;
    const float C1 = 1e-4f, C2 = 9e-4f;

    float4 ring[11];                 // 11-row vertical history (static idx only)
    #pragma unroll
    for (int u = 0; u < 11; ++u) ring[u] = make_float4(0.f,0.f,0.f,0.f);
    float4 vs = make_float4(0.f,0.f,0.f,0.f);   // running 11-row column box
    float accl = 0.f;

// Zero-register staging: per-lane global address, HW scatters lane*4 into LDS.
#define GLD(gp, lp) __builtin_amdgcn_global_load_lds( \
    (const __attribute__((address_space(1))) void*)(const void*)(gp), \
    (__attribute__((address_space(3))) void*)(void*)(lp), 4, 0, 0)

#define STAGE(rr) do { \
    const int gyc_ = min(max(gy0 + (rr), 0), H - 1); \
    const int soff_ = (gyc_ << 9) + gxc; \
    GLD(pb0 + soff_, &stage[(rr) % RNG][0][0]); \
    GLD(pb1 + soff_, &stage[(rr) % RNG][1][0]); \
    GLD(pb2 + soff_, &stage[(rr) % RNG][2][0]); \
    GLD(gb0 + soff_, &stage[(rr) % RNG][3][0]); \
    GLD(gb1 + soff_, &stage[(rr) % RNG][4][0]); \
    GLD(gb2 + soff_, &stage[(rr) % RNG][5][0]); \
} while(0)

// Counted wait: rows issued-but-unneeded stay in flight (T4: never drain to 0
// mid-loop). All counts are compile-time literals (fully unrolled loop).
#define VWAIT(n) asm volatile("s_waitcnt vmcnt(%0)" :: "n"(n) : "memory")

#define RS(ri) do { \
    if ((ri) + D < IR) STAGE((ri) + D); \
    VWAIT(6 * (((ri) + D < IR) ? D : (IR - 1 - (ri)))); \
    const bool rowok_ = colok && ((unsigned)(gy0 + (ri)) < (unsigned)H); \
    const float m_ = rowok_ ? 1.f : 0.f; \
    const float p0 = stage[(ri) % RNG][0][lane] * m_; \
    const float p1 = stage[(ri) % RNG][1][lane] * m_; \
    const float p2 = stage[(ri) % RNG][2][lane] * m_; \
    const float g0 = stage[(ri) % RNG][3][lane] * m_; \
    const float g1 = stage[(ri) % RNG][4][lane] * m_; \
    const float g2 = stage[(ri) % RNG][5][lane] * m_; \
    float4 q; \
    q.x = p0 + p1 + p2; \
    q.y = g0 + g1 + g2; \
    q.z = fmaf(p0,p0, fmaf(p1,p1, fmaf(p2,p2, fmaf(g0,g0, fmaf(g1,g1, g2*g2))))); \
    q.w = fmaf(p0,g0, fmaf(p1,g1, p2*g2)); \
    vs.x += q.x - ring[(ri)%11].x; \
    vs.y += q.y - ring[(ri)%11].y; \
    vs.z += q.z - ring[(ri)%11].z; \
    vs.w += q.w - ring[(ri)%11].w; \
    ring[(ri)%11] = q; \
    if ((ri) >= 10) vsbuf[((ri)-10)&7][(lane + (((ri)-10)&7)) & 63] = vs; \
} while(0)

#define SSIM_ACC(S, oxv) do { \
    if ((unsigned)(oxv) < W) { \
        const float mu_p = (S).x * inv_n, mu_g = (S).y * inv_n; \
        const float varsum = ((S).z - (S).x*mu_p - (S).y*mu_g) * inv_nm1; \
        const float cov    = ((S).w - (S).x*mu_g) * inv_n; \
        const float num = (2.f*mu_p*mu_g + C1) * (2.f*cov + C2); \
        const float den = (mu_p*mu_p + mu_g*mu_g + C1) * (varsum + C2); \
        accl = fmaf(num, __builtin_amdgcn_rcpf(den + 1e-8f), accl); \
    } \
} while(0)

    // In-wave DS ordering only (single-wave block, no cross-wave sharing).
#define WAVE_LDS_FENCE() asm volatile("s_waitcnt lgkmcnt(0)" ::: "memory")

    // Horizontal 11-tap over the 8 buffered vs-rows; lane = (row r, group g).
    auto phase2 = [&]() {
        const int r  = lane & 7;
        const int g  = lane >> 3;
        const int jb = 7 * g;
        const int ox0 = tc * TW + jb;
        float4 B = vsbuf[r][(jb + r) & 63];
        #pragma unroll
        for (int k = 1; k < 11; ++k) f4add(B, vsbuf[r][(jb + k + r) & 63]);
        SSIM_ACC(B, ox0);
        #pragma unroll
        for (int sp = 1; sp < 7; ++sp) {
            if (jb + 10 + sp <= 63) {   // also implies center valid
                const float4 nw = vsbuf[r][(jb + 10 + sp + r) & 63];
                const float4 od = vsbuf[r][(jb + sp - 1 + r) & 63];
                B.x += nw.x - od.x; B.y += nw.y - od.y;
                B.z += nw.z - od.z; B.w += nw.w - od.w;
                SSIM_ACC(B, ox0 + sp);
            }
        }
    };

    // ---- prologue: fill D rows of the ring (the only full-latency cost) ----
    STAGE(0); STAGE(1); STAGE(2); STAGE(3); STAGE(4);
    STAGE(5); STAGE(6); STAGE(7); STAGE(8); STAGE(9);

    RS(0);  RS(1);  RS(2);  RS(3);  RS(4);  RS(5);  RS(6);  RS(7);  RS(8);
    RS(9);  RS(10); RS(11); RS(12); RS(13); RS(14); RS(15); RS(16); RS(17);
    WAVE_LDS_FENCE(); phase2();
    RS(18); RS(19); RS(20); RS(21); RS(22); RS(23); RS(24); RS(25);
    WAVE_LDS_FENCE(); phase2();
    RS(26); RS(27); RS(28); RS(29); RS(30); RS(31); RS(32); RS(33);
    WAVE_LDS_FENCE(); phase2();
    RS(34); RS(35); RS(36); RS(37); RS(38); RS(39); RS(40); RS(41);
    WAVE_LDS_FENCE(); phase2();

    // ---- wave reduce ----
    #pragma unroll
    for (int off = 32; off > 0; off >>= 1) accl += __shfl_down(accl, off);
    if (lane == 0) partial[bid] = accl;

#undef GLD
#undef STAGE
#undef VWAIT
#undef RS
#undef SSIM_ACC
#undef WAVE_LDS_FENCE
}

__global__ __launch_bounds__(256) void ssim_final_reduce(
    const float* __restrict__ partial, float* __restrict__ out)
{
    __shared__ float red[4];
    const int tid = threadIdx.x;
    float s = 0.f;
    for (int i = tid; i < NBLOCKS; i += 256) s += partial[i];
    #pragma unroll
    for (int off = 32; off > 0; off >>= 1) s += __shfl_down(s, off);
    if ((tid & 63) == 0) red[tid >> 6] = s;
    __syncthreads();
    if (tid == 0) {
        const float total = red[0] + red[1] + red[2] + red[3];
        out[0] = 1.0f - total * (1.0f / (float)(BATCH * H * W));
    }
}

extern "C" void kernel_launch(void* const* d_in, const int* in_sizes, int n_in,
                              void* d_out, int out_size, void* d_ws, size_t ws_size,
                              hipStream_t stream) {
    const float* pred = (const float*)d_in[0];
    const float* gt   = (const float*)d_in[1];
    float* out        = (float*)d_out;
    float* partial    = (float*)d_ws;

    ssim_wave_kernel<<<NBLOCKS, 64, 0, stream>>>(pred, gt, partial);
    ssim_final_reduce<<<1, 256, 0, stream>>>(partial, out);
}

// Round 16
// 34.797 us; speedup vs baseline: 2.4074x; 1.0898x over previous
//
#include <hip/hip_runtime.h>

#define HALO 5
#define TW 48              // output cols per tile (sstart = 48tc-5 == 3 mod 4)
#define ROWS 32            // output rows per tile
#define IR (ROWS + 2*HALO) // 42 input rows
#define BATCH 16
#define CH 3
#define H 512
#define W 512
#define HW (H*W)
#define NCT 11             // 10 full 48-col tiles + 32-col remainder
#define NST (H/ROWS)       // 16 row strips
#define NBLOCKS (BATCH*NST*NCT)   // 2816
#define DPF 8              // prefetch distance (rows)
#define RNGC 16            // staging ring chunks (1 KB each)
#define NCHUNK 63          // 252 row-planes / 4

__device__ __forceinline__ void f4add(float4& a, const float4 b) {
    a.x += b.x; a.y += b.y; a.z += b.z; a.w += b.w;
}

__global__ __launch_bounds__(64) void ssim_wave_kernel(
    const float* __restrict__ pred, const float* __restrict__ gt,
    float* __restrict__ partial)
{
    // stg: 16-chunk ring; chunk c holds row-planes 4c..4c+3 (rp = 6*ri + p),
    //      each slice 256 B = 64 staged cols. Filled by global_load_lds x16.
    // vsbuf: 8-deep rotating vertical box sums, rotation-swizzled.
    __shared__ float  stg[RNGC][256];   // 16 KB
    __shared__ float4 vsbuf[8][64];     //  8 KB

    const int lane = threadIdx.x;
    const int bid  = (blockIdx.x & 7) * (NBLOCKS / 8) + (blockIdx.x >> 3);
    const int tc   = bid % NCT;
    const int rest = bid / NCT;
    const int ts   = rest & (NST - 1);
    const int b    = rest / NST;

    const int sstart = tc * TW - HALO;        // first needed input col
    const int g0     = sstart - 3;            // aligned staging start (shift=3)
    const int gx     = sstart + lane;         // owned column (lanes 0..57 used)
    const int gy0    = ts * ROWS - HALO;      // input row at ri=0
    const bool colok = (lane < TW + 2 * HALO) && ((unsigned)gx < W);

    const float* __restrict__ pb = pred + (size_t)b * (CH * HW);
    const float* __restrict__ gb = gt   + (size_t)b * (CH * HW);

    // ---- staging address precompute: slice s = lane>>4, quarter lane&15 ----
    // chunk c = 3t+j: rp = 12t + 4j + s -> plane (4j+s)%6, row 2t + (4j+s)/6
    const int s_   = lane >> 4;
    const int cg   = min(max(g0 + 4 * (lane & 15), 0), W - 4); // clamped col4
    const float* Bp[3];
    int dj[3];
    #pragma unroll
    for (int j = 0; j < 3; ++j) {
        const int a = 4 * j + s_;
        const int p = a % 6;
        dj[j] = a / 6;
        Bp[j] = ((p < 3) ? (pb + p * HW) : (gb + (p - 3) * HW)) + cg;
    }

    const float inv_n = 1.f/363.f, inv_nm1 = 1.f/362.f;
    const float C1 = 1e-4f, C2 = 9e-4f;

    float4 ring[11];
    #pragma unroll
    for (int u = 0; u < 11; ++u) ring[u] = make_float4(0.f,0.f,0.f,0.f);
    float4 vs = make_float4(0.f,0.f,0.f,0.f);
    float accl = 0.f;

    const float* sbase = &stg[0][0] + 3 + lane;   // consume base (shift=3)

#define GLD16(gp, lp) __builtin_amdgcn_global_load_lds( \
    (const __attribute__((address_space(1))) void*)(const void*)(gp), \
    (__attribute__((address_space(3))) void*)(void*)(lp), 16, 0, 0)

#define STAGE_CHUNK(c) do { \
    const int j_ = (c) % 3, t_ = (c) / 3; \
    const int gyc_ = min(max(gy0 + 2 * t_ + dj[j_], 0), H - 1); \
    GLD16(Bp[j_] + (gyc_ << 9), &stg[(c) & 15][0]); \
} while(0)

// chunk schedule (all compile-time): highest chunk issued before consuming ri
#define MIN2(a,b) ((a) < (b) ? (a) : (b))
#define CA(ri)    MIN2(NCHUNK - 1, (6 * (ri) + 6 * DPF + 5) >> 2)
#define CNEED(ri) ((6 * (ri) + 5) >> 2)

#define VWAIT(n) asm volatile("s_waitcnt vmcnt(%0)" :: "n"(n) : "memory")

// consume: 6 ds_read_b32, literal offsets off shared vaddr
#define LV(ri, p) sbase[(((6*(ri)+(p)) >> 2) & 15) * 256 + ((6*(ri)+(p)) & 3) * 64]

#define RS(ri) do { \
    for (int c_ = CA((ri) - 1) + 1; c_ <= CA(ri); ++c_) STAGE_CHUNK(c_); \
    VWAIT(CA(ri) - CNEED(ri)); \
    const bool rowok_ = colok && ((unsigned)(gy0 + (ri)) < (unsigned)H); \
    const float m_ = rowok_ ? 1.f : 0.f; \
    const float p0 = LV(ri,0) * m_; \
    const float p1 = LV(ri,1) * m_; \
    const float p2 = LV(ri,2) * m_; \
    const float g0v = LV(ri,3) * m_; \
    const float g1v = LV(ri,4) * m_; \
    const float g2v = LV(ri,5) * m_; \
    float4 q; \
    q.x = p0 + p1 + p2; \
    q.y = g0v + g1v + g2v; \
    q.z = fmaf(p0,p0, fmaf(p1,p1, fmaf(p2,p2, fmaf(g0v,g0v, fmaf(g1v,g1v, g2v*g2v))))); \
    q.w = fmaf(p0,g0v, fmaf(p1,g1v, p2*g2v)); \
    vs.x += q.x - ring[(ri)%11].x; \
    vs.y += q.y - ring[(ri)%11].y; \
    vs.z += q.z - ring[(ri)%11].z; \
    vs.w += q.w - ring[(ri)%11].w; \
    ring[(ri)%11] = q; \
    if ((ri) >= 10) vsbuf[((ri)-10)&7][(lane + (((ri)-10)&7)) & 63] = vs; \
} while(0)

#define SSIM_ACC(S, oxv) do { \
    if ((unsigned)(oxv) < W) { \
        const float mu_p = (S).x * inv_n, mu_g = (S).y * inv_n; \
        const float varsum = ((S).z - (S).x*mu_p - (S).y*mu_g) * inv_nm1; \
        const float cov    = ((S).w - (S).x*mu_g) * inv_n; \
        const float num = (2.f*mu_p*mu_g + C1) * (2.f*cov + C2); \
        const float den = (mu_p*mu_p + mu_g*mu_g + C1) * (varsum + C2); \
        accl = fmaf(num, __builtin_amdgcn_rcpf(den + 1e-8f), accl); \
    } \
} while(0)

#define WAVE_LDS_FENCE() asm volatile("s_waitcnt lgkmcnt(0)" ::: "memory")

    // Horizontal 11-tap over 8 buffered vs-rows; lane = (row r, group g of 6)
    auto phase2 = [&]() {
        const int r  = lane & 7;
        const int g  = lane >> 3;
        const int jb = 6 * g;                 // outputs jb..jb+5 (cols jb..jb+15)
        const int ox0 = tc * TW + jb;
        float4 B = vsbuf[r][(jb + r) & 63];
        #pragma unroll
        for (int k = 1; k < 11; ++k) f4add(B, vsbuf[r][(jb + k + r) & 63]);
        SSIM_ACC(B, ox0);
        #pragma unroll
        for (int sp = 1; sp < 6; ++sp) {
            const float4 nw = vsbuf[r][(jb + 10 + sp + r) & 63];
            const float4 od = vsbuf[r][(jb + sp - 1 + r) & 63];
            B.x += nw.x - od.x; B.y += nw.y - od.y;
            B.z += nw.z - od.z; B.w += nw.w - od.w;
            SSIM_ACC(B, ox0 + sp);
        }
    };

    // ---- prologue: issue chunks 0..CA(-1)=11 ----
    for (int c_ = 0; c_ <= CA(-1); ++c_) STAGE_CHUNK(c_);

    RS(0);  RS(1);  RS(2);  RS(3);  RS(4);  RS(5);  RS(6);  RS(7);  RS(8);
    RS(9);  RS(10); RS(11); RS(12); RS(13); RS(14); RS(15); RS(16); RS(17);
    WAVE_LDS_FENCE(); phase2();
    RS(18); RS(19); RS(20); RS(21); RS(22); RS(23); RS(24); RS(25);
    WAVE_LDS_FENCE(); phase2();
    RS(26); RS(27); RS(28); RS(29); RS(30); RS(31); RS(32); RS(33);
    WAVE_LDS_FENCE(); phase2();
    RS(34); RS(35); RS(36); RS(37); RS(38); RS(39); RS(40); RS(41);
    WAVE_LDS_FENCE(); phase2();

    // ---- wave reduce ----
    #pragma unroll
    for (int off = 32; off > 0; off >>= 1) accl += __shfl_down(accl, off);
    if (lane == 0) partial[bid] = accl;

#undef GLD16
#undef STAGE_CHUNK
#undef MIN2
#undef CA
#undef CNEED
#undef VWAIT
#undef LV
#undef RS
#undef SSIM_ACC
#undef WAVE_LDS_FENCE
}

__global__ __launch_bounds__(256) void ssim_final_reduce(
    const float* __restrict__ partial, float* __restrict__ out)
{
    __shared__ float red[4];
    const int tid = threadIdx.x;
    float s = 0.f;
    for (int i = tid; i < NBLOCKS; i += 256) s += partial[i];
    #pragma unroll
    for (int off = 32; off > 0; off >>= 1) s += __shfl_down(s, off);
    if ((tid & 63) == 0) red[tid >> 6] = s;
    __syncthreads();
    if (tid == 0) {
        const float total = red[0] + red[1] + red[2] + red[3];
        out[0] = 1.0f - total * (1.0f / (float)(BATCH * H * W));
    }
}

extern "C" void kernel_launch(void* const* d_in, const int* in_sizes, int n_in,
                              void* d_out, int out_size, void* d_ws, size_t ws_size,
                              hipStream_t stream) {
    const float* pred = (const float*)d_in[0];
    const float* gt   = (const float*)d_in[1];
    float* out        = (float*)d_out;
    float* partial    = (float*)d_ws;

    ssim_wave_kernel<<<NBLOCKS, 64, 0, stream>>>(pred, gt, partial);
    ssim_final_reduce<<<1, 256, 0, stream>>>(partial, out);
}